// Round 13
// baseline (229.184 us; speedup 1.0000x reference)
//
#include <hip/hip_runtime.h>

typedef __attribute__((ext_vector_type(4))) float f32x4;
typedef __attribute__((ext_vector_type(8))) __bf16 bf16x8;
typedef __attribute__((ext_vector_type(4))) __bf16 bf16x4;
typedef __attribute__((ext_vector_type(4))) int i32x4;

#define SXE (26624 * 512)   // elems of one [b][v] matrix, b=(n,l,c): 64*13*32 rows x 512

// ---------------- prep: x -> Xv2 bf16 [(n*13+l)*32+c][v]; also folds the A-cast ----------------
__global__ __launch_bounds__(256)
void prep_x(const float* __restrict__ x, __bf16* __restrict__ Xv2,
            const float* __restrict__ A, __bf16* __restrict__ Ab) {
  const int vt = blockIdx.x, n = blockIdx.y, tid = threadIdx.x;
  // folded cast_A: 768 slices of 256 float4 (3*512*512 floats total)
  if (vt < 12) {
    const int i = (n * 12 + vt) * 256 + tid;
    const float4 f = ((const float4*)A)[i];
    bf16x4 o;
    o[0] = (__bf16)f.x; o[1] = (__bf16)f.y; o[2] = (__bf16)f.z; o[3] = (__bf16)f.w;
    ((bf16x4*)Ab)[i] = o;
  }
  __shared__ float Xs[32 * 209];   // [c][v*13+l] for 16 v, pitch 209 (odd)
  const float* src = x + ((size_t)n * 32) * 6656 + vt * 16 * 13;
  for (int i = tid; i < 32 * 208; i += 256) {
    const int c = i / 208, r = i - c * 208;
    Xs[c * 209 + r] = src[(size_t)c * 6656 + r];
  }
  __syncthreads();
  for (int j = tid; j < 416; j += 256) {   // (l,c) rows, 16-v chunks
    const int c = j & 31, l = j >> 5;
    bf16x8 o8[2];
    #pragma unroll
    for (int v = 0; v < 16; ++v) o8[v >> 3][v & 7] = (__bf16)Xs[c * 209 + v * 13 + l];
    __bf16* d = Xv2 + (((size_t)n * 13 + l) * 32 + c) * 512 + vt * 16;
    *(bf16x8*)d = o8[0];
    *(bf16x8*)(d + 8) = o8[1];
  }
}

// ---------------- diffusion GEMM (R10/R12-verified best): 256x256, BK=64, 8 waves, dbuf, issue-early ----------------
__global__ __launch_bounds__(512, 2)
void gemm_bf16(const __bf16* __restrict__ Ab, const __bf16* __restrict__ SRC,
               __bf16* __restrict__ DSTB, size_t srcStride, size_t dstStride, int cpx) {
  extern __shared__ char gsm[];
  const int tid = threadIdx.x;
  const int lane = tid & 63, wid = tid >> 6, q = lane >> 4, r16 = lane & 15;

  const int bid = blockIdx.x;
  const int lg = (bid & 7) * cpx + (bid >> 3);   // grid % 8 == 0 -> bijective (m204)
  const int bx = lg / 6, r6 = lg % 6, s = r6 >> 1, by = r6 & 1;

  const __bf16* Amat = Ab + (size_t)s * 512 * 512;
  const __bf16* B = SRC + (size_t)s * srcStride;
  __bf16* D = DSTB + (size_t)s * dstStride;

  const int W0 = by * 256, B0 = bx * 256;
  const int wm = wid >> 2, wn = wid & 3;
  const int srow = lane >> 3, spos = lane & 7;

  f32x4 acc[8][4];
  #pragma unroll
  for (int m = 0; m < 8; ++m)
    #pragma unroll
    for (int n = 0; n < 4; ++n) acc[m][n] = {0.f, 0.f, 0.f, 0.f};

  auto STAGE = [&](int bufsel, int kt) {
    const int k0 = kt * 64;
    char* As = gsm + bufsel * 65536;
    char* Bs = As + 32768;
    #pragma unroll
    for (int i = 0; i < 4; ++i) {
      const int slot = i * 8 + wid;           // 32 slots x 1KB per tile
      const int r = slot * 8 + srow;          // tile row 0..255
      const int gc = spos ^ (r & 7);          // inverse-swizzled global source (rule 21)
      const __bf16* ga = Amat + (size_t)(W0 + r) * 512 + k0 + gc * 8;
      const __bf16* gb = B    + (size_t)(B0 + r) * 512 + k0 + gc * 8;
      __builtin_amdgcn_global_load_lds((const __attribute__((address_space(1))) unsigned int*)ga,
                                       (__attribute__((address_space(3))) unsigned int*)(As + slot * 1024 + lane * 16),
                                       16, 0, 0);
      __builtin_amdgcn_global_load_lds((const __attribute__((address_space(1))) unsigned int*)gb,
                                       (__attribute__((address_space(3))) unsigned int*)(Bs + slot * 1024 + lane * 16),
                                       16, 0, 0);
    }
  };

  STAGE(0, 0);
  __syncthreads();

  for (int t = 0; t < 8; ++t) {
    const int cur = t & 1;
    if (t < 7) STAGE(cur ^ 1, t + 1);        // issue-early: drains at end-of-iter barrier
    const char* As = gsm + cur * 65536;
    const char* Bs = As + 32768;
    #pragma unroll
    for (int ks = 0; ks < 2; ++ks) {
      const int ch = ks * 4 + q;
      bf16x8 af[4], df[8];
      #pragma unroll
      for (int n = 0; n < 4; ++n) {                    // A_s frags: rows = w
        const int r = wn * 64 + n * 16 + r16;
        af[n] = *(const bf16x8*)(As + r * 128 + ((ch ^ (r & 7)) << 4));
      }
      #pragma unroll
      for (int m = 0; m < 8; ++m) {                    // data frags: rows = b
        const int r = wm * 128 + m * 16 + r16;
        df[m] = *(const bf16x8*)(Bs + r * 128 + ((ch ^ (r & 7)) << 4));
      }
      __builtin_amdgcn_s_setprio(1);
      #pragma unroll
      for (int m = 0; m < 8; ++m)
        #pragma unroll
        for (int n = 0; n < 4; ++n)
          acc[m][n] = __builtin_amdgcn_mfma_f32_16x16x32_bf16(af[n], df[m], acc[m][n], 0, 0, 0);
      __builtin_amdgcn_s_setprio(0);
    }
    __syncthreads();
  }

  #pragma unroll
  for (int m = 0; m < 8; ++m) {
    const int b = B0 + wm * 128 + m * 16 + r16;
    #pragma unroll
    for (int n = 0; n < 4; ++n) {
      const int w = W0 + wn * 64 + n * 16 + q * 4;
      bf16x4 o4;
      o4[0] = (__bf16)acc[m][n][0]; o4[1] = (__bf16)acc[m][n][1];
      o4[2] = (__bf16)acc[m][n][2]; o4[3] = (__bf16)acc[m][n][3];
      *(bf16x4*)(D + (size_t)b * 512 + w) = o4;
    }
  }
}

// ---------------- temporal conv as MFMA: 128-v tile, 512 thr, 8 waves, 1 block/CU ----------------
// Hs[l(13)][c(32)][chunk'(16)x16B], chunk' = (v>>3) ^ ((c>>3)<<2)  -> <=2-way read conflicts
__global__ __launch_bounds__(512)
void conv_kernel(const __bf16* __restrict__ Xv2, const __bf16* __restrict__ Y1,
                 const __bf16* __restrict__ Y2, const float* __restrict__ W,
                 const float* __restrict__ bias, float* __restrict__ y) {
  extern __shared__ char sm[];   // Hs 106496 + Ws 6144 = 112640; Ds (90368) overlays Hs
  char* Ws = sm + 106496;
  const int vt = blockIdx.x;     // 4 tiles of 128 v
  const int n  = blockIdx.y;
  const int tid = threadIdx.x;
  const int lane = tid & 63, wave = tid >> 6, q = lane >> 4, r16 = lane & 15;

  const __bf16* gsrc[7] = {Xv2, Y1, Y2, Y1 + (size_t)SXE, Y2 + (size_t)SXE,
                           Y1 + 2 * (size_t)SXE, Y2 + 2 * (size_t)SXE};

  f32x4 acc[11][2];
  #pragma unroll
  for (int t = 0; t < 11; ++t) { acc[t][0] = {0,0,0,0}; acc[t][1] = {0,0,0,0}; }

  const int vv = wave * 16 + r16;          // this lane's v within 128-tile
  const int vch = vv >> 3;                 // 0..15
  const int vlo = (vv & 7) * 2;
  const int cst = tid >> 4, hst = tid & 15;          // staging: c, h (one l per iteration)
  const int gbase = q * 2048 + ((vch ^ (q << 2)) << 4) + vlo;   // read: c = q*8+j

  for (int g = 0; g < 7; ++g) {
    __syncthreads();
    const __bf16* src = gsrc[g] + ((size_t)n * 416) * 512 + vt * 128;
    #pragma unroll
    for (int l = 0; l < 13; ++l) {     // 512 thr cover 32 c x 16 h per l
      i32x4 val = *(const i32x4*)(src + ((size_t)(l * 32 + cst) << 9) + hst * 8);
      *(i32x4*)(sm + l * 8192 + cst * 256 + ((hst ^ ((cst >> 3) << 2)) << 4)) = val;
    }
    for (int idx = tid; idx < 768; idx += 512) {   // W frags (R7-verified build)
      const int f = idx >> 7, rem2 = idx & 127, lw = rem2 >> 1, half = rem2 & 1;
      const int kt = f >> 1, of = f & 1;
      const int o = of * 16 + (lw & 15);
      const int cc = g * 32 + (lw >> 4) * 8 + half * 4;
      bf16x4 w4;
      #pragma unroll
      for (int j = 0; j < 4; ++j)
        w4[j] = (__bf16)W[((size_t)o * 224 + cc + j) * 3 + kt];
      *(bf16x4*)(Ws + idx * 8) = w4;
    }
    __syncthreads();

    bf16x8 a8[13];
    #pragma unroll
    for (int l = 0; l < 13; ++l) {
      bf16x8 a;
      #pragma unroll
      for (int j = 0; j < 8; ++j)
        a[j] = *(const __bf16*)(sm + l * 8192 + gbase + j * 256);
      a8[l] = a;
    }
    bf16x8 wf[6];
    #pragma unroll
    for (int f = 0; f < 6; ++f)
      wf[f] = *(const bf16x8*)(Ws + (f * 64 + lane) * 16);

    #pragma unroll
    for (int kt = 0; kt < 3; ++kt)
      #pragma unroll
      for (int of = 0; of < 2; ++of)
        #pragma unroll
        for (int t = 0; t < 11; ++t)
          acc[t][of] = __builtin_amdgcn_mfma_f32_16x16x32_bf16(a8[t + kt], wf[kt * 2 + of], acc[t][of], 0, 0, 0);
  }

  // epilogue: two passes of 16 o via Ds[o16][v(128)][t(11)] f32 (pitch 1412), coalesced stores
  float* Ds = (float*)sm;
  const int o16 = lane & 15;
  #pragma unroll
  for (int p = 0; p < 2; ++p) {
    __syncthreads();
    #pragma unroll
    for (int t = 0; t < 11; ++t) {
      const int vbase = wave * 16 + q * 4;
      #pragma unroll
      for (int rg = 0; rg < 4; ++rg)
        Ds[o16 * 1412 + (vbase + rg) * 11 + t] = acc[t][p][rg];
    }
    __syncthreads();
    #pragma unroll
    for (int i = 0; i < 11; ++i) {
      const int cg = tid + i * 512;            // 16 o x 352 f32x4-chunks
      const int oo = cg / 352, ch = cg - oo * 352;
      f32x4 v4 = *(const f32x4*)(Ds + oo * 1412 + ch * 4);
      const float bo = bias[p * 16 + oo];
      v4[0] += bo; v4[1] += bo; v4[2] += bo; v4[3] += bo;
      float* yp = y + (((size_t)n * 32 + p * 16 + oo) * 512 + vt * 128) * 11 + ch * 4;
      *(f32x4*)yp = v4;
    }
  }
}

extern "C" void kernel_launch(void* const* d_in, const int* in_sizes, int n_in,
                              void* d_out, int out_size, void* d_ws, size_t ws_size,
                              hipStream_t stream) {
  (void)in_sizes; (void)n_in; (void)out_size; (void)ws_size;
  const float* x = (const float*)d_in[0];
  const float* A = (const float*)d_in[1];
  const float* W = (const float*)d_in[2];
  const float* b = (const float*)d_in[3];
  float* y = (float*)d_out;

  // ws: Xv2 (27.3 MB) + Y1 x3 (81.8) + Y2 x3 (81.8) + Ab (1.6) = 192.4 MB (known-good)
  char* ws = (char*)d_ws;
  const size_t SXB = (size_t)SXE * 2;
  __bf16* Xv2 = (__bf16*)ws;
  __bf16* Y1  = (__bf16*)(ws + SXB);
  __bf16* Y2  = (__bf16*)(ws + 4 * SXB);
  __bf16* Ab  = (__bf16*)(ws + 7 * SXB);

  prep_x<<<dim3(32, 64), 256, 0, stream>>>(x, Xv2, A, Ab);
  // grid = 104 bx * 2 by * 3 s = 624 = 8 * 78 (bijective swizzle; cpx = 78); 128KB dynamic LDS
  gemm_bf16<<<dim3(624), 512, 131072, stream>>>(Ab, Xv2, Y1, 0, (size_t)SXE, 78);
  gemm_bf16<<<dim3(624), 512, 131072, stream>>>(Ab, Y1, Y2, (size_t)SXE, (size_t)SXE, 78);
  conv_kernel<<<dim3(4, 64), 512, 112640, stream>>>(Xv2, Y1, Y2, W, b, y);
}

// Round 14
// 208.630 us; speedup vs baseline: 1.0985x; 1.0985x over previous
//
#include <hip/hip_runtime.h>

typedef __attribute__((ext_vector_type(4))) float f32x4;
typedef __attribute__((ext_vector_type(8))) __bf16 bf16x8;
typedef __attribute__((ext_vector_type(4))) __bf16 bf16x4;
typedef __attribute__((ext_vector_type(4))) int i32x4;

#define SXE (26624 * 512)   // elems of one [b][v] matrix, b=(n,l,c): 64*13*32 rows x 512

// ---------------- prep: x -> Xv2 bf16 [(n*13+l)*32+c][v]; folds the A-cast ----------------
__global__ __launch_bounds__(256)
void prep_x(const float* __restrict__ x, __bf16* __restrict__ Xv2,
            const float* __restrict__ A, __bf16* __restrict__ Ab) {
  const int vt = blockIdx.x, n = blockIdx.y, tid = threadIdx.x;
  if (vt < 12) {   // folded cast_A: 768 slices of 256 float4
    const int i = (n * 12 + vt) * 256 + tid;
    const float4 f = ((const float4*)A)[i];
    bf16x4 o;
    o[0] = (__bf16)f.x; o[1] = (__bf16)f.y; o[2] = (__bf16)f.z; o[3] = (__bf16)f.w;
    ((bf16x4*)Ab)[i] = o;
  }
  __shared__ float Xs[32 * 209];   // [c][v*13+l] for 16 v, pitch 209 (odd)
  const float* src = x + ((size_t)n * 32) * 6656 + vt * 16 * 13;
  for (int i = tid; i < 32 * 208; i += 256) {
    const int c = i / 208, r = i - c * 208;
    Xs[c * 209 + r] = src[(size_t)c * 6656 + r];
  }
  __syncthreads();
  for (int j = tid; j < 416; j += 256) {   // (l,c) rows, 16-v chunks
    const int c = j & 31, l = j >> 5;
    bf16x8 o8[2];
    #pragma unroll
    for (int v = 0; v < 16; ++v) o8[v >> 3][v & 7] = (__bf16)Xs[c * 209 + v * 13 + l];
    __bf16* d = Xv2 + (((size_t)n * 13 + l) * 32 + c) * 512 + vt * 16;
    *(bf16x8*)d = o8[0];
    *(bf16x8*)(d + 8) = o8[1];
  }
}

// ---------------- diffusion GEMM (R10/R12-verified best): 256x256, BK=64, 8 waves, dbuf, issue-early ----------------
__global__ __launch_bounds__(512, 2)
void gemm_bf16(const __bf16* __restrict__ Ab, const __bf16* __restrict__ SRC,
               __bf16* __restrict__ DSTB, size_t srcStride, size_t dstStride, int cpx) {
  extern __shared__ char gsm[];
  const int tid = threadIdx.x;
  const int lane = tid & 63, wid = tid >> 6, q = lane >> 4, r16 = lane & 15;

  const int bid = blockIdx.x;
  const int lg = (bid & 7) * cpx + (bid >> 3);   // grid % 8 == 0 -> bijective (m204)
  const int bx = lg / 6, r6 = lg % 6, s = r6 >> 1, by = r6 & 1;

  const __bf16* Amat = Ab + (size_t)s * 512 * 512;
  const __bf16* B = SRC + (size_t)s * srcStride;
  __bf16* D = DSTB + (size_t)s * dstStride;

  const int W0 = by * 256, B0 = bx * 256;
  const int wm = wid >> 2, wn = wid & 3;
  const int srow = lane >> 3, spos = lane & 7;

  f32x4 acc[8][4];
  #pragma unroll
  for (int m = 0; m < 8; ++m)
    #pragma unroll
    for (int n = 0; n < 4; ++n) acc[m][n] = {0.f, 0.f, 0.f, 0.f};

  auto STAGE = [&](int bufsel, int kt) {
    const int k0 = kt * 64;
    char* As = gsm + bufsel * 65536;
    char* Bs = As + 32768;
    #pragma unroll
    for (int i = 0; i < 4; ++i) {
      const int slot = i * 8 + wid;           // 32 slots x 1KB per tile
      const int r = slot * 8 + srow;          // tile row 0..255
      const int gc = spos ^ (r & 7);          // inverse-swizzled global source (rule 21)
      const __bf16* ga = Amat + (size_t)(W0 + r) * 512 + k0 + gc * 8;
      const __bf16* gb = B    + (size_t)(B0 + r) * 512 + k0 + gc * 8;
      __builtin_amdgcn_global_load_lds((const __attribute__((address_space(1))) unsigned int*)ga,
                                       (__attribute__((address_space(3))) unsigned int*)(As + slot * 1024 + lane * 16),
                                       16, 0, 0);
      __builtin_amdgcn_global_load_lds((const __attribute__((address_space(1))) unsigned int*)gb,
                                       (__attribute__((address_space(3))) unsigned int*)(Bs + slot * 1024 + lane * 16),
                                       16, 0, 0);
    }
  };

  STAGE(0, 0);
  __syncthreads();

  for (int t = 0; t < 8; ++t) {
    const int cur = t & 1;
    if (t < 7) STAGE(cur ^ 1, t + 1);        // issue-early: drains at end-of-iter barrier
    const char* As = gsm + cur * 65536;
    const char* Bs = As + 32768;
    #pragma unroll
    for (int ks = 0; ks < 2; ++ks) {
      const int ch = ks * 4 + q;
      bf16x8 af[4], df[8];
      #pragma unroll
      for (int n = 0; n < 4; ++n) {                    // A_s frags: rows = w
        const int r = wn * 64 + n * 16 + r16;
        af[n] = *(const bf16x8*)(As + r * 128 + ((ch ^ (r & 7)) << 4));
      }
      #pragma unroll
      for (int m = 0; m < 8; ++m) {                    // data frags: rows = b
        const int r = wm * 128 + m * 16 + r16;
        df[m] = *(const bf16x8*)(Bs + r * 128 + ((ch ^ (r & 7)) << 4));
      }
      __builtin_amdgcn_s_setprio(1);
      #pragma unroll
      for (int m = 0; m < 8; ++m)
        #pragma unroll
        for (int n = 0; n < 4; ++n)
          acc[m][n] = __builtin_amdgcn_mfma_f32_16x16x32_bf16(af[n], df[m], acc[m][n], 0, 0, 0);
      __builtin_amdgcn_s_setprio(0);
    }
    __syncthreads();
  }

  #pragma unroll
  for (int m = 0; m < 8; ++m) {
    const int b = B0 + wm * 128 + m * 16 + r16;
    #pragma unroll
    for (int n = 0; n < 4; ++n) {
      const int w = W0 + wn * 64 + n * 16 + q * 4;
      bf16x4 o4;
      o4[0] = (__bf16)acc[m][n][0]; o4[1] = (__bf16)acc[m][n][1];
      o4[2] = (__bf16)acc[m][n][2]; o4[3] = (__bf16)acc[m][n][3];
      *(bf16x4*)(D + (size_t)b * 512 + w) = o4;
    }
  }
}

// ---------------- temporal conv as MFMA: 64-v tile (R12 shape) + T14 reg-prefetch of next group ----------------
__global__ __launch_bounds__(256, 2)
void conv_kernel(const __bf16* __restrict__ Xv2, const __bf16* __restrict__ Y1,
                 const __bf16* __restrict__ Y2, const float* __restrict__ W,
                 const float* __restrict__ bias, float* __restrict__ y) {
  const int vt = blockIdx.x;   // 8 tiles of 64 v
  const int n  = blockIdx.y;
  const int tid = threadIdx.x;
  const int lane = tid & 63, wave = tid >> 6, q = lane >> 4, r16 = lane & 15;

  __shared__ char sm[59392];   // Hs 53248 + Ws 6144; Ds overlays Hs
  char* Ws = sm + 53248;

  const __bf16* gsrc[7] = {Xv2, Y1, Y2, Y1 + (size_t)SXE, Y2 + (size_t)SXE,
                           Y1 + 2 * (size_t)SXE, Y2 + 2 * (size_t)SXE};

  f32x4 acc[11][2];
  #pragma unroll
  for (int t = 0; t < 11; ++t) { acc[t][0] = {0,0,0,0}; acc[t][1] = {0,0,0,0}; }

  const int vv = wave * 16 + r16;          // this lane's v within 64-tile
  const int vch = vv >> 3;
  const int vlo = (vv & 7) * 2;
  // staging decomposition (per thread, 13 chunks): l = it, c = tid>>3, h = tid&7
  const int cst = tid >> 3, hst = tid & 7;
  const size_t goff = ((size_t)cst << 9) + hst * 8;
  const int lds_off = cst * 128 + ((hst ^ ((cst >> 3) << 1)) << 4);   // swizzled chunk pos
  const int gbase = q * 1024 + (((vch ^ (q << 1)) & 7) << 4) + vlo;   // gather: c = q*8+j

  const size_t base = ((size_t)n * 416) * 512 + vt * 64;

  // T14: prefetch group 0 into registers
  i32x4 hreg[13];
  {
    const __bf16* src = gsrc[0] + base;
    #pragma unroll
    for (int l = 0; l < 13; ++l)
      hreg[l] = *(const i32x4*)(src + (size_t)l * 16384 + goff);
  }

  for (int g = 0; g < 7; ++g) {
    __syncthreads();   // previous group's reads done -> safe to overwrite Hs
    #pragma unroll
    for (int l = 0; l < 13; ++l)
      *(i32x4*)(sm + l * 4096 + lds_off) = hreg[l];
    for (int idx = tid; idx < 768; idx += 256) {   // W frags (R7-verified build)
      const int f = idx >> 7, rem2 = idx & 127, lw = rem2 >> 1, half = rem2 & 1;
      const int kt = f >> 1, of = f & 1;
      const int o = of * 16 + (lw & 15);
      const int cc = g * 32 + (lw >> 4) * 8 + half * 4;
      bf16x4 w4;
      #pragma unroll
      for (int j = 0; j < 4; ++j)
        w4[j] = (__bf16)W[((size_t)o * 224 + cc + j) * 3 + kt];
      *(bf16x4*)(Ws + idx * 8) = w4;
    }
    __syncthreads();

    // T14: issue next group's loads NOW; latency hides under gather+MFMA below
    if (g < 6) {
      const __bf16* srcn = gsrc[g + 1] + base;
      #pragma unroll
      for (int l = 0; l < 13; ++l)
        hreg[l] = *(const i32x4*)(srcn + (size_t)l * 16384 + goff);
    }

    bf16x8 a8[13];
    #pragma unroll
    for (int l = 0; l < 13; ++l) {
      bf16x8 a;
      #pragma unroll
      for (int j = 0; j < 8; ++j)
        a[j] = *(const __bf16*)(sm + l * 4096 + gbase + j * 128);
      a8[l] = a;
    }
    bf16x8 wf[6];
    #pragma unroll
    for (int f = 0; f < 6; ++f)
      wf[f] = *(const bf16x8*)(Ws + (f * 64 + lane) * 16);

    #pragma unroll
    for (int kt = 0; kt < 3; ++kt)
      #pragma unroll
      for (int of = 0; of < 2; ++of)
        #pragma unroll
        for (int t = 0; t < 11; ++t)
          acc[t][of] = __builtin_amdgcn_mfma_f32_16x16x32_bf16(a8[t + kt], wf[kt * 2 + of], acc[t][of], 0, 0, 0);
  }

  // epilogue: two passes of 16 o via Ds[o16][v(64)][t(11)] f32 (pitch 708), coalesced stores
  float* Ds = (float*)sm;
  const int o16 = lane & 15;
  #pragma unroll
  for (int p = 0; p < 2; ++p) {
    __syncthreads();
    #pragma unroll
    for (int t = 0; t < 11; ++t) {
      const int vbase = wave * 16 + q * 4;
      #pragma unroll
      for (int rg = 0; rg < 4; ++rg)
        Ds[o16 * 708 + (vbase + rg) * 11 + t] = acc[t][p][rg];
    }
    __syncthreads();
    #pragma unroll
    for (int i = 0; i < 11; ++i) {
      const int cg = tid + i * 256;            // 16 o x 176 f32x4-chunks
      const int oo = cg / 176, ch = cg - oo * 176;
      f32x4 v4 = *(const f32x4*)(Ds + oo * 708 + ch * 4);
      const float bo = bias[p * 16 + oo];
      v4[0] += bo; v4[1] += bo; v4[2] += bo; v4[3] += bo;
      float* yp = y + (((size_t)n * 32 + p * 16 + oo) * 512 + vt * 64) * 11 + ch * 4;
      *(f32x4*)yp = v4;
    }
  }
}

extern "C" void kernel_launch(void* const* d_in, const int* in_sizes, int n_in,
                              void* d_out, int out_size, void* d_ws, size_t ws_size,
                              hipStream_t stream) {
  (void)in_sizes; (void)n_in; (void)out_size; (void)ws_size;
  const float* x = (const float*)d_in[0];
  const float* A = (const float*)d_in[1];
  const float* W = (const float*)d_in[2];
  const float* b = (const float*)d_in[3];
  float* y = (float*)d_out;

  // ws: Xv2 (27.3 MB) + Y1 x3 (81.8) + Y2 x3 (81.8) + Ab (1.6) = 192.4 MB (known-good)
  char* ws = (char*)d_ws;
  const size_t SXB = (size_t)SXE * 2;
  __bf16* Xv2 = (__bf16*)ws;
  __bf16* Y1  = (__bf16*)(ws + SXB);
  __bf16* Y2  = (__bf16*)(ws + 4 * SXB);
  __bf16* Ab  = (__bf16*)(ws + 7 * SXB);

  prep_x<<<dim3(32, 64), 256, 0, stream>>>(x, Xv2, A, Ab);
  // grid = 104 bx * 2 by * 3 s = 624 = 8 * 78 (bijective swizzle; cpx = 78); 128KB dynamic LDS
  gemm_bf16<<<dim3(624), 512, 131072, stream>>>(Ab, Xv2, Y1, 0, (size_t)SXE, 78);
  gemm_bf16<<<dim3(624), 512, 131072, stream>>>(Ab, Y1, Y2, (size_t)SXE, (size_t)SXE, 78);
  conv_kernel<<<dim3(8, 64), 256, 0, stream>>>(Xv2, Y1, Y2, W, b, y);
}